// Round 1
// baseline (1587.860 us; speedup 1.0000x reference)
//
#include <hip/hip_runtime.h>

// Problem constants (from reference)
#define NUM_F   26
#define DIM     128
#define NROWS   100000
#define BATCH   4096
#define TLEN    81920   // B * L indices per feature

// One 64-lane wave per (feature, bag).
// Pair-gather scheme: lanes 0-31 load row idx[2p], lanes 32-63 load row idx[2p+1];
// each lane loads a float4 (16 B), so one global_load_dwordx4 fetches TWO rows (1 KB).
// 8 pair-loads (16 rows, 8 KB) are kept in flight per group for latency hiding.
// Cross-half partial sums are folded with shfl_xor(32) before the store.
__global__ __launch_bounds__(256) void ebag_kernel(
    const float* __restrict__ tables,   // [F, N, D] fp32
    const int*   __restrict__ values,   // [F, T] int32
    const int*   __restrict__ offsets,  // [F, B+1] int32
    float*       __restrict__ out)      // [B, F, D] fp32
{
    const int wid  = blockIdx.x * 4 + (threadIdx.x >> 6);   // global wave id
    const int lane = threadIdx.x & 63;
    if (wid >= NUM_F * BATCH) return;

    const int f = wid >> 12;            // wid / BATCH  (feature-major for L3 locality)
    const int b = wid & (BATCH - 1);    // wid % BATCH

    const int off_base = f * (BATCH + 1) + b;
    const int start = offsets[off_base];
    const int end   = offsets[off_base + 1];

    const float* __restrict__ tab  = tables + (size_t)f * NROWS * DIM;
    const int*   __restrict__ vals = values + (size_t)f * TLEN;

    const int      hi   = lane >> 5;               // which row of the pair this lane loads
    const unsigned colB = (unsigned)(lane & 31) * 16u;  // byte offset of lane's float4 in a row

    float a0 = 0.0f, a1 = 0.0f, a2 = 0.0f, a3 = 0.0f;

    // Load a pair of rows: lanes<32 read row iA, lanes>=32 read row iB.
    // Row byte offset = row * 512 (< 2^26, fits 32-bit) -> SGPR base + VGPR offset.
#define PAIR_LOAD(vv, jj)                                                   \
    {                                                                       \
        const int iA = __builtin_amdgcn_readlane(myidx, (jj));              \
        const int iB = __builtin_amdgcn_readlane(myidx, (jj) + 1);          \
        const int row = hi ? iB : iA;                                       \
        const unsigned off = ((unsigned)row << 9) + colB;                   \
        vv = *(const float4*)((const char*)tab + off);                      \
    }

    for (int i0 = start; i0 < end; i0 += 64) {
        const int cnt = min(64, end - i0);
        int myidx = 0;
        if (i0 + lane < end) myidx = vals[i0 + lane];

        int j = 0;
        // Main: 8 pair-loads = 16 rows = 8 KB in flight before any wait.
        for (; j + 16 <= cnt; j += 16) {
            float4 v0, v1, v2, v3, v4, v5, v6, v7;
            PAIR_LOAD(v0, j + 0);
            PAIR_LOAD(v1, j + 2);
            PAIR_LOAD(v2, j + 4);
            PAIR_LOAD(v3, j + 6);
            PAIR_LOAD(v4, j + 8);
            PAIR_LOAD(v5, j + 10);
            PAIR_LOAD(v6, j + 12);
            PAIR_LOAD(v7, j + 14);
            a0 += (v0.x + v1.x) + (v2.x + v3.x) + (v4.x + v5.x) + (v6.x + v7.x);
            a1 += (v0.y + v1.y) + (v2.y + v3.y) + (v4.y + v5.y) + (v6.y + v7.y);
            a2 += (v0.z + v1.z) + (v2.z + v3.z) + (v4.z + v5.z) + (v6.z + v7.z);
            a3 += (v0.w + v1.w) + (v2.w + v3.w) + (v4.w + v5.w) + (v6.w + v7.w);
        }
        // Pair tail.
        for (; j + 2 <= cnt; j += 2) {
            float4 v0;
            PAIR_LOAD(v0, j);
            a0 += v0.x; a1 += v0.y; a2 += v0.z; a3 += v0.w;
        }
        // Odd final row: only lanes 0-31 participate.
        if (j < cnt) {
            const int iA = __builtin_amdgcn_readlane(myidx, j);
            if (lane < 32) {
                const unsigned off = ((unsigned)iA << 9) + colB;
                const float4 v = *(const float4*)((const char*)tab + off);
                a0 += v.x; a1 += v.y; a2 += v.z; a3 += v.w;
            }
        }
    }
#undef PAIR_LOAD

    // Fold the two half-wave partial sums (lanes l and l+32 hold the same columns).
    a0 += __shfl_xor(a0, 32);
    a1 += __shfl_xor(a1, 32);
    a2 += __shfl_xor(a2, 32);
    a3 += __shfl_xor(a3, 32);

    // out[b, f, :] — 32 lanes x float4 = 512 B row. Empty bags write zeros
    // (harness poisons d_out, so every element must be written).
    if (lane < 32) {
        float4 r; r.x = a0; r.y = a1; r.z = a2; r.w = a3;
        ((float4*)(out + ((size_t)b * NUM_F + f) * DIM))[lane] = r;
    }
}

extern "C" void kernel_launch(void* const* d_in, const int* in_sizes, int n_in,
                              void* d_out, int out_size, void* d_ws, size_t ws_size,
                              hipStream_t stream) {
    const float* tables  = (const float*)d_in[0];
    const int*   values  = (const int*)d_in[1];
    const int*   offsets = (const int*)d_in[2];
    float*       out     = (float*)d_out;

    const int total_waves = NUM_F * BATCH;          // 106,496 bags
    const int blocks = total_waves / 4;             // 4 waves per 256-thr block
    ebag_kernel<<<dim3(blocks), dim3(256), 0, stream>>>(tables, values, offsets, out);
}